// Round 10
// baseline (360.226 us; speedup 1.0000x reference)
//
#include <hip/hip_runtime.h>

#define D 64
#define LAYERS 3
#define BSHIFT 8                 // bucket = dst >> 8 (256 nodes per bucket)
#define NBMAX 512                // max buckets supported (N <= 131072)
#define CHUNK 4096               // edges per pass-1 block (256 thr x 16)

typedef unsigned short ushort_t;
typedef __bf16 bf16x8 __attribute__((ext_vector_type(8)));
typedef float f32x4 __attribute__((ext_vector_type(4)));

__device__ __forceinline__ ushort_t f2bf(float f) {           // RNE float->bf16
    unsigned b = __float_as_uint(f);
    b += 0x7FFFu + ((b >> 16) & 1u);
    return (ushort_t)(b >> 16);
}
__device__ __forceinline__ float bflo(unsigned u) { return __uint_as_float(u << 16); }
__device__ __forceinline__ float bfhi(unsigned u) { return __uint_as_float(u & 0xFFFF0000u); }

// ---------------- one-time pre-conversions ----------------
// x fp32 -> bf16 (8 elems/thread)
__global__ __launch_bounds__(256) void conv_x_kernel(
    const float* __restrict__ x, ushort_t* __restrict__ xb, int n)
{
    const int g = blockIdx.x * 256 + threadIdx.x;
    const int i = g * 8;
    if (i >= n) return;
    const float4 x0 = *(const float4*)(x + i);
    const float4 x1 = *(const float4*)(x + i + 4);
    uint4 u;
    u.x = (unsigned)f2bf(x0.x) | ((unsigned)f2bf(x0.y) << 16);
    u.y = (unsigned)f2bf(x0.z) | ((unsigned)f2bf(x0.w) << 16);
    u.z = (unsigned)f2bf(x1.x) | ((unsigned)f2bf(x1.y) << 16);
    u.w = (unsigned)f2bf(x1.z) | ((unsigned)f2bf(x1.w) << 16);
    *(uint4*)(xb + i) = u;
}

// W[l][m][k][n] fp32 -> wtb[(l*4+m)][n][k] bf16 (transposed, MFMA-B layout)
__global__ __launch_bounds__(256) void conv_w_kernel(
    const float* __restrict__ Wq, const float* __restrict__ Wk,
    const float* __restrict__ Wv, const float* __restrict__ Ws,
    ushort_t* __restrict__ wtb)
{
    const int b = blockIdx.x;          // l*4 + m
    const int l = b >> 2, m = b & 3;
    const float* W = ((m == 0) ? Wq : (m == 1) ? Wk : (m == 2) ? Wv : Ws)
                     + (size_t)l * D * D;
    ushort_t* out = wtb + (size_t)b * D * D;
    const int t = threadIdx.x;
#pragma unroll
    for (int i = 0; i < 16; ++i) {
        const int e = i * 256 + t;       // 0..4095
        const int n = e >> 6, k = e & 63;
        out[n * D + k] = f2bf(W[k * D + n]);
    }
}

// ---------------- projections via MFMA (LDS-free, all-bf16) ----------------
// Per block: 32 rows. Wave w computes h@W[w]: 0=q, 1=k, 2=v, 3=skip.
// A and B fragments load directly from global (B is 32 KB, L2-resident).
__global__ __launch_bounds__(256) void proj_kernel(
    const ushort_t* __restrict__ hb,          // [N][64] bf16 input
    const ushort_t* __restrict__ wtb_l,       // [4][64][64] bf16 W^T
    const float* __restrict__ bq, const float* __restrict__ bk,
    const float* __restrict__ bv, const float* __restrict__ bs,
    ushort_t* __restrict__ qb, ushort_t* __restrict__ kv,
    ushort_t* __restrict__ sk, int N)
{
    const int t = threadIdx.x;
    const int block_row = blockIdx.x * 32;
    const int l  = t & 63;
    const int w  = t >> 6;            // wave id: 0=q,1=k,2=v,3=skip
    const int lr = l & 15;
    const int hi = l >> 4;
    const int lk = hi * 8;

    // A fragments: rows rt*16+lr, k = ks*32+lk+[0..7]
    bf16x8 afr[2][2];
#pragma unroll
    for (int rt = 0; rt < 2; ++rt) {
        const int row = block_row + rt * 16 + lr;
        const size_t base = (size_t)min(row, N - 1) * D;
#pragma unroll
        for (int ks = 0; ks < 2; ++ks)
            afr[rt][ks] = *(const bf16x8*)(hb + base + ks * 32 + lk);
    }

    const ushort_t* wtw = wtb_l + (size_t)w * D * D;
    f32x4 acc[2][4];
#pragma unroll
    for (int rt = 0; rt < 2; ++rt)
#pragma unroll
        for (int ct = 0; ct < 4; ++ct)
            acc[rt][ct] = (f32x4){0.f, 0.f, 0.f, 0.f};

#pragma unroll
    for (int ct = 0; ct < 4; ++ct) {
        const bf16x8 b0 = *(const bf16x8*)(wtw + (ct * 16 + lr) * D + lk);
        const bf16x8 b1 = *(const bf16x8*)(wtw + (ct * 16 + lr) * D + 32 + lk);
        acc[0][ct] = __builtin_amdgcn_mfma_f32_16x16x32_bf16(afr[0][0], b0, acc[0][ct], 0, 0, 0);
        acc[0][ct] = __builtin_amdgcn_mfma_f32_16x16x32_bf16(afr[0][1], b1, acc[0][ct], 0, 0, 0);
        acc[1][ct] = __builtin_amdgcn_mfma_f32_16x16x32_bf16(afr[1][0], b0, acc[1][ct], 0, 0, 0);
        acc[1][ct] = __builtin_amdgcn_mfma_f32_16x16x32_bf16(afr[1][1], b1, acc[1][ct], 0, 0, 0);
    }

    const float* biasW = (w == 0) ? bq : (w == 1) ? bk : (w == 2) ? bv : bs;
    float bcol[4];
#pragma unroll
    for (int ct = 0; ct < 4; ++ct) bcol[ct] = biasW[ct * 16 + lr];

#pragma unroll
    for (int rt = 0; rt < 2; ++rt) {
#pragma unroll
        for (int ct = 0; ct < 4; ++ct) {
#pragma unroll
            for (int r = 0; r < 4; ++r) {
                const int row = block_row + rt * 16 + hi * 4 + r;
                const int col = ct * 16 + lr;
                if (row < N) {
                    const float val = acc[rt][ct][r] + bcol[ct];
                    if (w == 0)      qb[(size_t)row * D + col] = f2bf(val);
                    else if (w == 3) sk[(size_t)row * D + col] = f2bf(val);
                    else {
                        ushort_t* kvr = kv + (size_t)row * 128;
                        kvr[(col >> 2) * 8 + ((w == 2) ? 4 : 0) + (col & 3)] = f2bf(val);
                    }
                }
            }
        }
    }
}

// ---------------- two-pass bucketed counting sort ----------------
__global__ __launch_bounds__(256) void b_hist_kernel(
    const int* __restrict__ dst, int* __restrict__ bcount, int E)
{
    __shared__ int h[NBMAX];
    const int t = threadIdx.x;
    h[t] = 0; h[t + 256] = 0;
    __syncthreads();
    const int base = blockIdx.x * CHUNK;
#pragma unroll
    for (int i = 0; i < 16; ++i) {
        const int e = base + i * 256 + t;
        if (e < E) atomicAdd(h + (dst[e] >> BSHIFT), 1);
    }
    __syncthreads();
    if (h[t])       atomicAdd(bcount + t, h[t]);
    if (h[t + 256]) atomicAdd(bcount + t + 256, h[t + 256]);
}

__global__ __launch_bounds__(512) void b_scan_kernel(
    const int* __restrict__ bcount, int* __restrict__ bbase,
    int* __restrict__ gcursor, int E)
{
    __shared__ int tmp[NBMAX];
    const int t = threadIdx.x;
    const int val = bcount[t];
    tmp[t] = val;
    __syncthreads();
    for (int off = 1; off < NBMAX; off <<= 1) {
        int x = (t >= off) ? tmp[t - off] : 0;
        __syncthreads();
        tmp[t] += x;
        __syncthreads();
    }
    const int excl = tmp[t] - val;
    bbase[t] = excl;
    gcursor[t] = excl;
    if (t == NBMAX - 1) bbase[NBMAX] = E;
}

// packed record: (dst & 255) << 24 | src   (needs N < 2^24)
__global__ __launch_bounds__(256) void b_scatter_kernel(
    const int* __restrict__ src, const int* __restrict__ dst,
    int* __restrict__ gcursor, unsigned* __restrict__ packed, int E)
{
    __shared__ int h[NBMAX];
    __shared__ int gb[NBMAX];
    const int t = threadIdx.x;
    h[t] = 0; h[t + 256] = 0;
    __syncthreads();

    const int base = blockIdx.x * CHUNK;
    int ls[16], ld[16], lr[16];
#pragma unroll
    for (int i = 0; i < 16; ++i) {
        const int e = base + i * 256 + t;
        if (e < E) {
            ls[i] = src[e];
            ld[i] = dst[e];
            lr[i] = atomicAdd(h + (ld[i] >> BSHIFT), 1);
        }
    }
    __syncthreads();
    for (int b = t; b < NBMAX; b += 256) {
        const int c = h[b];
        gb[b] = c ? atomicAdd(gcursor + b, c) : 0;
    }
    __syncthreads();
#pragma unroll
    for (int i = 0; i < 16; ++i) {
        const int e = base + i * 256 + t;
        if (e < E) {
            const int pos = gb[ld[i] >> BSHIFT] + lr[i];
            packed[pos] = ((unsigned)(ld[i] & 255) << 24) | (unsigned)ls[i];
        }
    }
}

__global__ __launch_bounds__(256) void b_final_kernel(
    const unsigned* __restrict__ packed, const int* __restrict__ bbase,
    int* __restrict__ esrc, int* __restrict__ offs, int* __restrict__ counts,
    int N)
{
    __shared__ int hist[256];
    __shared__ int scan[256];
    __shared__ int cursor[256];
    const int t = threadIdx.x;
    const int b = blockIdx.x;
    const int s = bbase[b];
    const int e = bbase[b + 1];

    hist[t] = 0;
    __syncthreads();
    for (int j = s + t; j < e; j += 256) {
        atomicAdd(hist + (packed[j] >> 24), 1);
    }
    __syncthreads();
    const int val = hist[t];
    scan[t] = val;
    __syncthreads();
    for (int off = 1; off < 256; off <<= 1) {
        int x = (t >= off) ? scan[t - off] : 0;
        __syncthreads();
        scan[t] += x;
        __syncthreads();
    }
    const int excl = scan[t] - val;
    const int node = b * 256 + t;
    if (node < N) {
        counts[node] = val;
        offs[node]   = s + excl;
    }
    cursor[t] = excl;
    __syncthreads();
    for (int j = s + t; j < e; j += 256) {
        const unsigned p = packed[j];
        const int r = atomicAdd(cursor + (p >> 24), 1);
        esrc[s + r] = (int)(p & 0xFFFFFFu);
    }
}

// ---------------- fused per-node attention ----------------
// 16 lanes/node, dst-sorted edges, online softmax. q/skip bf16 in;
// out = agg + skip, written bf16 (+relu) or fp32 (final layer).
__global__ __launch_bounds__(256) void node_kernel(
    const ushort_t* __restrict__ qb, const uint4* __restrict__ kv,
    const int* __restrict__ esrc, const int* __restrict__ offs,
    const int* __restrict__ counts, const ushort_t* __restrict__ sk,
    ushort_t* __restrict__ hb_out, float* __restrict__ hf_out,
    int N, int mode)                  // mode 0: bf16+relu, 1: fp32 no relu
{
    const int t = threadIdx.x;
    const int lane = t & 15;
    const int node = blockIdx.x * 16 + (t >> 4);
    if (node >= N) return;

    const int start = offs[node];
    const int end   = start + counts[node];

    const uint2 qu = *(const uint2*)(qb + (size_t)node * D + lane * 4);
    float4 qv;
    qv.x = bflo(qu.x); qv.y = bfhi(qu.x);
    qv.z = bflo(qu.y); qv.w = bfhi(qu.y);

    float m = -INFINITY, ssum = 0.0f;
    float4 acc = make_float4(0.0f, 0.0f, 0.0f, 0.0f);

    int j = start;
    for (; j + 2 <= end; j += 2) {
        const int s0 = esrc[j];
        const int s1 = esrc[j + 1];
        const uint4 u0 = kv[(size_t)s0 * 16 + lane];
        const uint4 u1 = kv[(size_t)s1 * 16 + lane];

        float p0 = bflo(u0.x) * qv.x + bfhi(u0.x) * qv.y
                 + bflo(u0.y) * qv.z + bfhi(u0.y) * qv.w;
        float p1 = bflo(u1.x) * qv.x + bfhi(u1.x) * qv.y
                 + bflo(u1.y) * qv.z + bfhi(u1.y) * qv.w;
        p0 += __shfl_xor(p0, 1);  p1 += __shfl_xor(p1, 1);
        p0 += __shfl_xor(p0, 2);  p1 += __shfl_xor(p1, 2);
        p0 += __shfl_xor(p0, 4);  p1 += __shfl_xor(p1, 4);
        p0 += __shfl_xor(p0, 8);  p1 += __shfl_xor(p1, 8);
        p0 *= 0.125f;  p1 *= 0.125f;

        const float mx = fmaxf(p0, p1);
        if (mx > m) {
            const float sc = __expf(m - mx);
            ssum *= sc;
            acc.x *= sc; acc.y *= sc; acc.z *= sc; acc.w *= sc;
            m = mx;
        }
        const float w0 = __expf(p0 - m);
        const float w1 = __expf(p1 - m);
        ssum += w0 + w1;
        acc.x = fmaf(w0, bflo(u0.z), fmaf(w1, bflo(u1.z), acc.x));
        acc.y = fmaf(w0, bfhi(u0.z), fmaf(w1, bfhi(u1.z), acc.y));
        acc.z = fmaf(w0, bflo(u0.w), fmaf(w1, bflo(u1.w), acc.z));
        acc.w = fmaf(w0, bfhi(u0.w), fmaf(w1, bfhi(u1.w), acc.w));
    }
    if (j < end) {
        const int s0 = esrc[j];
        const uint4 u0 = kv[(size_t)s0 * 16 + lane];
        float p0 = bflo(u0.x) * qv.x + bfhi(u0.x) * qv.y
                 + bflo(u0.y) * qv.z + bfhi(u0.y) * qv.w;
        p0 += __shfl_xor(p0, 1);
        p0 += __shfl_xor(p0, 2);
        p0 += __shfl_xor(p0, 4);
        p0 += __shfl_xor(p0, 8);
        p0 *= 0.125f;
        if (p0 > m) {
            const float sc = __expf(m - p0);
            ssum *= sc;
            acc.x *= sc; acc.y *= sc; acc.z *= sc; acc.w *= sc;
            m = p0;
        }
        const float w0 = __expf(p0 - m);
        ssum += w0;
        acc.x = fmaf(w0, bflo(u0.z), acc.x);
        acc.y = fmaf(w0, bfhi(u0.z), acc.y);
        acc.z = fmaf(w0, bflo(u0.w), acc.z);
        acc.w = fmaf(w0, bfhi(u0.w), acc.w);
    }

    const float inv = 1.0f / (ssum + 1e-16f);
    const uint2 su = *(const uint2*)(sk + (size_t)node * D + lane * 4);
    float4 ov;
    ov.x = fmaf(acc.x, inv, bflo(su.x));
    ov.y = fmaf(acc.y, inv, bfhi(su.x));
    ov.z = fmaf(acc.z, inv, bflo(su.y));
    ov.w = fmaf(acc.w, inv, bfhi(su.y));
    if (mode == 0) {
        ov.x = fmaxf(ov.x, 0.0f); ov.y = fmaxf(ov.y, 0.0f);
        ov.z = fmaxf(ov.z, 0.0f); ov.w = fmaxf(ov.w, 0.0f);
        uint2 u;
        u.x = (unsigned)f2bf(ov.x) | ((unsigned)f2bf(ov.y) << 16);
        u.y = (unsigned)f2bf(ov.z) | ((unsigned)f2bf(ov.w) << 16);
        *(uint2*)(hb_out + (size_t)node * D + lane * 4) = u;
    } else {
        *(float4*)(hf_out + (size_t)node * D + lane * 4) = ov;
    }
}

extern "C" void kernel_launch(void* const* d_in, const int* in_sizes, int n_in,
                              void* d_out, int out_size, void* d_ws, size_t ws_size,
                              hipStream_t stream)
{
    const float* x   = (const float*)d_in[0];
    const int* ei    = (const int*)d_in[1];
    const float* Wq  = (const float*)d_in[3];
    const float* bq  = (const float*)d_in[4];
    const float* Wk  = (const float*)d_in[5];
    const float* bk  = (const float*)d_in[6];
    const float* Wv  = (const float*)d_in[7];
    const float* bv  = (const float*)d_in[8];
    const float* Ws  = (const float*)d_in[9];
    const float* bs  = (const float*)d_in[10];

    const int N = in_sizes[0] / D;
    const int E = in_sizes[2];
    const int* src = ei;
    const int* dst = ei + E;
    const int NB = (N + 255) / 256;

    // workspace layout (ushorts first)
    ushort_t* xb  = (ushort_t*)d_ws;                // N*64 bf16 (layer-0 input)
    ushort_t* hb0 = xb  + (size_t)N * D;            // N*64 bf16
    ushort_t* hb1 = hb0 + (size_t)N * D;            // N*64 bf16
    ushort_t* qb  = hb1 + (size_t)N * D;            // N*64 bf16
    ushort_t* sk  = qb  + (size_t)N * D;            // N*64 bf16
    ushort_t* kv  = sk  + (size_t)N * D;            // N*128 bf16
    ushort_t* wtb = kv  + (size_t)N * 128;          // L*4*4096 bf16
    int* esrc     = (int*)(wtb + LAYERS * 4 * D * D); // E
    unsigned* packed = (unsigned*)(esrc + E);       // E
    int* counts  = (int*)(packed + E);              // NBMAX*256
    int* offs    = counts + NBMAX * 256;            // NBMAX*256
    int* bcount  = offs + NBMAX * 256;              // NBMAX
    int* bbase   = bcount + NBMAX;                  // NBMAX+1
    int* gcursor = bbase + NBMAX + 1;               // NBMAX

    // ---- one-time conversions + edge sort ----
    conv_x_kernel<<<(N * D + 2047) / 2048, 256, 0, stream>>>(x, xb, N * D);
    conv_w_kernel<<<LAYERS * 4, 256, 0, stream>>>(Wq, Wk, Wv, Ws, wtb);

    hipMemsetAsync(bcount, 0, NBMAX * 4, stream);
    const int p1_blocks = (E + CHUNK - 1) / CHUNK;
    b_hist_kernel<<<p1_blocks, 256, 0, stream>>>(dst, bcount, E);
    b_scan_kernel<<<1, NBMAX, 0, stream>>>(bcount, bbase, gcursor, E);
    b_scatter_kernel<<<p1_blocks, 256, 0, stream>>>(src, dst, gcursor, packed, E);
    b_final_kernel<<<NB, 256, 0, stream>>>(packed, bbase, esrc, offs, counts, N);

    const int proj_blocks = (N + 31) / 32;
    const int node_blocks = (N + 15) / 16;

    const ushort_t* cur = xb;
    for (int l = 0; l < LAYERS; ++l) {
        const int last = (l == LAYERS - 1);
        ushort_t* hb_out = (l & 1) ? hb1 : hb0;

        proj_kernel<<<proj_blocks, 256, 0, stream>>>(
            cur, wtb + (size_t)l * 4 * D * D,
            bq + (size_t)l * D, bk + (size_t)l * D,
            bv + (size_t)l * D, bs + (size_t)l * D,
            qb, kv, sk, N);

        node_kernel<<<node_blocks, 256, 0, stream>>>(
            qb, (const uint4*)kv, esrc, offs, counts, sk,
            hb_out, (float*)d_out, N, last ? 1 : 0);

        cur = hb_out;
    }
}

// Round 11
// 343.819 us; speedup vs baseline: 1.0477x; 1.0477x over previous
//
#include <hip/hip_runtime.h>

#define D 64
#define LAYERS 3
#define BSHIFT 8                 // bucket = dst >> 8 (256 nodes per bucket)
#define NBMAX 512                // max buckets supported (N <= 131072)
#define CHUNK 4096               // edges per pass-1 block (256 thr x 16)

typedef unsigned short ushort_t;
typedef __bf16 bf16x8 __attribute__((ext_vector_type(8)));
typedef float f32x4 __attribute__((ext_vector_type(4)));

__device__ __forceinline__ ushort_t f2bf(float f) {           // RNE float->bf16
    unsigned b = __float_as_uint(f);
    b += 0x7FFFu + ((b >> 16) & 1u);
    return (ushort_t)(b >> 16);
}
__device__ __forceinline__ float bflo(unsigned u) { return __uint_as_float(u << 16); }
__device__ __forceinline__ float bfhi(unsigned u) { return __uint_as_float(u & 0xFFFF0000u); }

// ---------------- one-time pre-conversions (fused) ----------------
// blocks [0, L*4): W[l][m][k][n] fp32 -> wtb[(l*4+m)][n][k] bf16
// blocks [L*4, ...): x fp32 -> bf16, 8 elems/thread
__global__ __launch_bounds__(256) void conv_kernel(
    const float* __restrict__ x, ushort_t* __restrict__ xb, int n,
    const float* __restrict__ Wq, const float* __restrict__ Wk,
    const float* __restrict__ Wv, const float* __restrict__ Ws,
    ushort_t* __restrict__ wtb)
{
    const int t = threadIdx.x;
    if (blockIdx.x < LAYERS * 4) {
        const int b = blockIdx.x;
        const int l = b >> 2, m = b & 3;
        const float* W = ((m == 0) ? Wq : (m == 1) ? Wk : (m == 2) ? Wv : Ws)
                         + (size_t)l * D * D;
        ushort_t* out = wtb + (size_t)b * D * D;
#pragma unroll
        for (int i = 0; i < 16; ++i) {
            const int e = i * 256 + t;
            const int nn = e >> 6, k = e & 63;
            out[nn * D + k] = f2bf(W[k * D + nn]);
        }
    } else {
        const int g = (blockIdx.x - LAYERS * 4) * 256 + t;
        const int i = g * 8;
        if (i >= n) return;
        const float4 x0 = *(const float4*)(x + i);
        const float4 x1 = *(const float4*)(x + i + 4);
        uint4 u;
        u.x = (unsigned)f2bf(x0.x) | ((unsigned)f2bf(x0.y) << 16);
        u.y = (unsigned)f2bf(x0.z) | ((unsigned)f2bf(x0.w) << 16);
        u.z = (unsigned)f2bf(x1.x) | ((unsigned)f2bf(x1.y) << 16);
        u.w = (unsigned)f2bf(x1.z) | ((unsigned)f2bf(x1.w) << 16);
        *(uint4*)(xb + i) = u;
    }
}

// ---------------- projections via MFMA + LDS store-staging ----------------
// Per block: 32 rows. Wave w computes h@W[w]: 0=q, 1=k, 2=v, 3=skip.
// Fragments land in LDS (kv pre-interleaved); writeback is fully coalesced
// uint4 stores (fixes the scattered-2B-store RFO pathology).
__global__ __launch_bounds__(256) void proj_kernel(
    const ushort_t* __restrict__ hb,          // [N][64] bf16 input
    const ushort_t* __restrict__ wtb_l,       // [4][64][64] bf16 W^T
    const float* __restrict__ bq, const float* __restrict__ bk,
    const float* __restrict__ bv, const float* __restrict__ bs,
    ushort_t* __restrict__ qb, ushort_t* __restrict__ kv,
    ushort_t* __restrict__ sk, int N)
{
    __shared__ ushort_t outq[32][72];         // 72/136: padded, 16B-aligned rows
    __shared__ ushort_t outs[32][72];
    __shared__ ushort_t outkv[32][136];

    const int t = threadIdx.x;
    const int block_row = blockIdx.x * 32;
    const int l  = t & 63;
    const int w  = t >> 6;            // wave id: 0=q,1=k,2=v,3=skip
    const int lr = l & 15;
    const int hi = l >> 4;
    const int lk = hi * 8;

    // A fragments: rows rt*16+lr, k = ks*32+lk+[0..7]
    bf16x8 afr[2][2];
#pragma unroll
    for (int rt = 0; rt < 2; ++rt) {
        const int row = block_row + rt * 16 + lr;
        const size_t base = (size_t)min(row, N - 1) * D;
#pragma unroll
        for (int ks = 0; ks < 2; ++ks)
            afr[rt][ks] = *(const bf16x8*)(hb + base + ks * 32 + lk);
    }

    const ushort_t* wtw = wtb_l + (size_t)w * D * D;
    f32x4 acc[2][4];
#pragma unroll
    for (int rt = 0; rt < 2; ++rt)
#pragma unroll
        for (int ct = 0; ct < 4; ++ct)
            acc[rt][ct] = (f32x4){0.f, 0.f, 0.f, 0.f};

#pragma unroll
    for (int ct = 0; ct < 4; ++ct) {
        const bf16x8 b0 = *(const bf16x8*)(wtw + (ct * 16 + lr) * D + lk);
        const bf16x8 b1 = *(const bf16x8*)(wtw + (ct * 16 + lr) * D + 32 + lk);
        acc[0][ct] = __builtin_amdgcn_mfma_f32_16x16x32_bf16(afr[0][0], b0, acc[0][ct], 0, 0, 0);
        acc[0][ct] = __builtin_amdgcn_mfma_f32_16x16x32_bf16(afr[0][1], b1, acc[0][ct], 0, 0, 0);
        acc[1][ct] = __builtin_amdgcn_mfma_f32_16x16x32_bf16(afr[1][0], b0, acc[1][ct], 0, 0, 0);
        acc[1][ct] = __builtin_amdgcn_mfma_f32_16x16x32_bf16(afr[1][1], b1, acc[1][ct], 0, 0, 0);
    }

    const float* biasW = (w == 0) ? bq : (w == 1) ? bk : (w == 2) ? bv : bs;
    float bcol[4];
#pragma unroll
    for (int ct = 0; ct < 4; ++ct) bcol[ct] = biasW[ct * 16 + lr];

    // fragments -> LDS (unconditional; global guards in writeback)
#pragma unroll
    for (int rt = 0; rt < 2; ++rt) {
#pragma unroll
        for (int ct = 0; ct < 4; ++ct) {
#pragma unroll
            for (int r = 0; r < 4; ++r) {
                const int row = rt * 16 + hi * 4 + r;
                const int col = ct * 16 + lr;
                const ushort_t vb = f2bf(acc[rt][ct][r] + bcol[ct]);
                if (w == 0)      outq[row][col] = vb;
                else if (w == 3) outs[row][col] = vb;
                else             outkv[row][(col >> 2) * 8 + ((w == 2) ? 4 : 0) + (col & 3)] = vb;
            }
        }
    }
    __syncthreads();

    // coalesced writeback: 8 threads per row
    const int row  = t >> 3;
    const int ch   = (t & 7) * 8;     // qb/sk chunk (ushorts)
    const int ckv  = (t & 7) * 16;    // kv chunk (ushorts)
    const int grow = block_row + row;
    if (grow < N) {
        *(uint4*)(qb + (size_t)grow * 64 + ch)       = *(const uint4*)&outq[row][ch];
        *(uint4*)(sk + (size_t)grow * 64 + ch)       = *(const uint4*)&outs[row][ch];
        *(uint4*)(kv + (size_t)grow * 128 + ckv)     = *(const uint4*)&outkv[row][ckv];
        *(uint4*)(kv + (size_t)grow * 128 + ckv + 8) = *(const uint4*)&outkv[row][ckv + 8];
    }
}

// ---------------- two-pass bucketed counting sort ----------------
__global__ __launch_bounds__(256) void b_hist_kernel(
    const int* __restrict__ dst, int* __restrict__ bcount, int E)
{
    __shared__ int h[NBMAX];
    const int t = threadIdx.x;
    h[t] = 0; h[t + 256] = 0;
    __syncthreads();
    const int base = blockIdx.x * CHUNK;
#pragma unroll
    for (int i = 0; i < 16; ++i) {
        const int e = base + i * 256 + t;
        if (e < E) atomicAdd(h + (dst[e] >> BSHIFT), 1);
    }
    __syncthreads();
    if (h[t])       atomicAdd(bcount + t, h[t]);
    if (h[t + 256]) atomicAdd(bcount + t + 256, h[t + 256]);
}

__global__ __launch_bounds__(512) void b_scan_kernel(
    const int* __restrict__ bcount, int* __restrict__ bbase,
    int* __restrict__ gcursor, int E)
{
    __shared__ int tmp[NBMAX];
    const int t = threadIdx.x;
    const int val = bcount[t];
    tmp[t] = val;
    __syncthreads();
    for (int off = 1; off < NBMAX; off <<= 1) {
        int x = (t >= off) ? tmp[t - off] : 0;
        __syncthreads();
        tmp[t] += x;
        __syncthreads();
    }
    const int excl = tmp[t] - val;
    bbase[t] = excl;
    gcursor[t] = excl;
    if (t == NBMAX - 1) bbase[NBMAX] = E;
}

// packed record: (dst & 255) << 24 | src   (needs N < 2^24)
__global__ __launch_bounds__(256) void b_scatter_kernel(
    const int* __restrict__ src, const int* __restrict__ dst,
    int* __restrict__ gcursor, unsigned* __restrict__ packed, int E)
{
    __shared__ int h[NBMAX];
    __shared__ int gb[NBMAX];
    const int t = threadIdx.x;
    h[t] = 0; h[t + 256] = 0;
    __syncthreads();

    const int base = blockIdx.x * CHUNK;
    int ls[16], ld[16], lr[16];
#pragma unroll
    for (int i = 0; i < 16; ++i) {
        const int e = base + i * 256 + t;
        if (e < E) {
            ls[i] = src[e];
            ld[i] = dst[e];
            lr[i] = atomicAdd(h + (ld[i] >> BSHIFT), 1);
        }
    }
    __syncthreads();
    for (int b = t; b < NBMAX; b += 256) {
        const int c = h[b];
        gb[b] = c ? atomicAdd(gcursor + b, c) : 0;
    }
    __syncthreads();
#pragma unroll
    for (int i = 0; i < 16; ++i) {
        const int e = base + i * 256 + t;
        if (e < E) {
            const int pos = gb[ld[i] >> BSHIFT] + lr[i];
            packed[pos] = ((unsigned)(ld[i] & 255) << 24) | (unsigned)ls[i];
        }
    }
}

__global__ __launch_bounds__(256) void b_final_kernel(
    const unsigned* __restrict__ packed, const int* __restrict__ bbase,
    int* __restrict__ esrc, int* __restrict__ offs, int* __restrict__ counts,
    int N)
{
    __shared__ int hist[256];
    __shared__ int scan[256];
    __shared__ int cursor[256];
    const int t = threadIdx.x;
    const int b = blockIdx.x;
    const int s = bbase[b];
    const int e = bbase[b + 1];

    hist[t] = 0;
    __syncthreads();
    for (int j = s + t; j < e; j += 256) {
        atomicAdd(hist + (packed[j] >> 24), 1);
    }
    __syncthreads();
    const int val = hist[t];
    scan[t] = val;
    __syncthreads();
    for (int off = 1; off < 256; off <<= 1) {
        int x = (t >= off) ? scan[t - off] : 0;
        __syncthreads();
        scan[t] += x;
        __syncthreads();
    }
    const int excl = scan[t] - val;
    const int node = b * 256 + t;
    if (node < N) {
        counts[node] = val;
        offs[node]   = s + excl;
    }
    cursor[t] = excl;
    __syncthreads();
    for (int j = s + t; j < e; j += 256) {
        const unsigned p = packed[j];
        const int r = atomicAdd(cursor + (p >> 24), 1);
        esrc[s + r] = (int)(p & 0xFFFFFFu);
    }
}

// ---------------- fused per-node attention ----------------
// 16 lanes/node, dst-sorted edges, online softmax. q/skip bf16 in;
// out = agg + skip, written bf16 (+relu) or fp32 (final layer).
__global__ __launch_bounds__(256) void node_kernel(
    const ushort_t* __restrict__ qb, const uint4* __restrict__ kv,
    const int* __restrict__ esrc, const int* __restrict__ offs,
    const int* __restrict__ counts, const ushort_t* __restrict__ sk,
    ushort_t* __restrict__ hb_out, float* __restrict__ hf_out,
    int N, int mode)                  // mode 0: bf16+relu, 1: fp32 no relu
{
    const int t = threadIdx.x;
    const int lane = t & 15;
    const int node = blockIdx.x * 16 + (t >> 4);
    if (node >= N) return;

    const int start = offs[node];
    const int end   = start + counts[node];

    const uint2 qu = *(const uint2*)(qb + (size_t)node * D + lane * 4);
    float4 qv;
    qv.x = bflo(qu.x); qv.y = bfhi(qu.x);
    qv.z = bflo(qu.y); qv.w = bfhi(qu.y);

    float m = -INFINITY, ssum = 0.0f;
    float4 acc = make_float4(0.0f, 0.0f, 0.0f, 0.0f);

    int j = start;
    for (; j + 2 <= end; j += 2) {
        const int s0 = esrc[j];
        const int s1 = esrc[j + 1];
        const uint4 u0 = kv[(size_t)s0 * 16 + lane];
        const uint4 u1 = kv[(size_t)s1 * 16 + lane];

        float p0 = bflo(u0.x) * qv.x + bfhi(u0.x) * qv.y
                 + bflo(u0.y) * qv.z + bfhi(u0.y) * qv.w;
        float p1 = bflo(u1.x) * qv.x + bfhi(u1.x) * qv.y
                 + bflo(u1.y) * qv.z + bfhi(u1.y) * qv.w;
        p0 += __shfl_xor(p0, 1);  p1 += __shfl_xor(p1, 1);
        p0 += __shfl_xor(p0, 2);  p1 += __shfl_xor(p1, 2);
        p0 += __shfl_xor(p0, 4);  p1 += __shfl_xor(p1, 4);
        p0 += __shfl_xor(p0, 8);  p1 += __shfl_xor(p1, 8);
        p0 *= 0.125f;  p1 *= 0.125f;

        const float mx = fmaxf(p0, p1);
        if (mx > m) {
            const float sc = __expf(m - mx);
            ssum *= sc;
            acc.x *= sc; acc.y *= sc; acc.z *= sc; acc.w *= sc;
            m = mx;
        }
        const float w0 = __expf(p0 - m);
        const float w1 = __expf(p1 - m);
        ssum += w0 + w1;
        acc.x = fmaf(w0, bflo(u0.z), fmaf(w1, bflo(u1.z), acc.x));
        acc.y = fmaf(w0, bfhi(u0.z), fmaf(w1, bfhi(u1.z), acc.y));
        acc.z = fmaf(w0, bflo(u0.w), fmaf(w1, bflo(u1.w), acc.z));
        acc.w = fmaf(w0, bfhi(u0.w), fmaf(w1, bfhi(u1.w), acc.w));
    }
    if (j < end) {
        const int s0 = esrc[j];
        const uint4 u0 = kv[(size_t)s0 * 16 + lane];
        float p0 = bflo(u0.x) * qv.x + bfhi(u0.x) * qv.y
                 + bflo(u0.y) * qv.z + bfhi(u0.y) * qv.w;
        p0 += __shfl_xor(p0, 1);
        p0 += __shfl_xor(p0, 2);
        p0 += __shfl_xor(p0, 4);
        p0 += __shfl_xor(p0, 8);
        p0 *= 0.125f;
        if (p0 > m) {
            const float sc = __expf(m - p0);
            ssum *= sc;
            acc.x *= sc; acc.y *= sc; acc.z *= sc; acc.w *= sc;
            m = p0;
        }
        const float w0 = __expf(p0 - m);
        ssum += w0;
        acc.x = fmaf(w0, bflo(u0.z), acc.x);
        acc.y = fmaf(w0, bfhi(u0.z), acc.y);
        acc.z = fmaf(w0, bflo(u0.w), acc.z);
        acc.w = fmaf(w0, bfhi(u0.w), acc.w);
    }

    const float inv = 1.0f / (ssum + 1e-16f);
    const uint2 su = *(const uint2*)(sk + (size_t)node * D + lane * 4);
    float4 ov;
    ov.x = fmaf(acc.x, inv, bflo(su.x));
    ov.y = fmaf(acc.y, inv, bfhi(su.x));
    ov.z = fmaf(acc.z, inv, bflo(su.y));
    ov.w = fmaf(acc.w, inv, bfhi(su.y));
    if (mode == 0) {
        ov.x = fmaxf(ov.x, 0.0f); ov.y = fmaxf(ov.y, 0.0f);
        ov.z = fmaxf(ov.z, 0.0f); ov.w = fmaxf(ov.w, 0.0f);
        uint2 u;
        u.x = (unsigned)f2bf(ov.x) | ((unsigned)f2bf(ov.y) << 16);
        u.y = (unsigned)f2bf(ov.z) | ((unsigned)f2bf(ov.w) << 16);
        *(uint2*)(hb_out + (size_t)node * D + lane * 4) = u;
    } else {
        *(float4*)(hf_out + (size_t)node * D + lane * 4) = ov;
    }
}

extern "C" void kernel_launch(void* const* d_in, const int* in_sizes, int n_in,
                              void* d_out, int out_size, void* d_ws, size_t ws_size,
                              hipStream_t stream)
{
    const float* x   = (const float*)d_in[0];
    const int* ei    = (const int*)d_in[1];
    const float* Wq  = (const float*)d_in[3];
    const float* bq  = (const float*)d_in[4];
    const float* Wk  = (const float*)d_in[5];
    const float* bk  = (const float*)d_in[6];
    const float* Wv  = (const float*)d_in[7];
    const float* bv  = (const float*)d_in[8];
    const float* Ws  = (const float*)d_in[9];
    const float* bs  = (const float*)d_in[10];

    const int N = in_sizes[0] / D;
    const int E = in_sizes[2];
    const int* src = ei;
    const int* dst = ei + E;
    const int NB = (N + 255) / 256;

    // workspace layout (ushorts first)
    ushort_t* xb  = (ushort_t*)d_ws;                // N*64 bf16 (layer-0 input)
    ushort_t* hb0 = xb  + (size_t)N * D;            // N*64 bf16
    ushort_t* hb1 = hb0 + (size_t)N * D;            // N*64 bf16
    ushort_t* qb  = hb1 + (size_t)N * D;            // N*64 bf16
    ushort_t* sk  = qb  + (size_t)N * D;            // N*64 bf16
    ushort_t* kv  = sk  + (size_t)N * D;            // N*128 bf16
    ushort_t* wtb = kv  + (size_t)N * 128;          // L*4*4096 bf16
    int* esrc     = (int*)(wtb + LAYERS * 4 * D * D); // E
    unsigned* packed = (unsigned*)(esrc + E);       // E
    int* counts  = (int*)(packed + E);              // NBMAX*256
    int* offs    = counts + NBMAX * 256;            // NBMAX*256
    int* bcount  = offs + NBMAX * 256;              // NBMAX
    int* bbase   = bcount + NBMAX;                  // NBMAX+1
    int* gcursor = bbase + NBMAX + 1;               // NBMAX

    // ---- one-time conversions (fused) + edge sort ----
    const int conv_x_blocks = (N * D + 2047) / 2048;
    conv_kernel<<<LAYERS * 4 + conv_x_blocks, 256, 0, stream>>>(
        x, xb, N * D, Wq, Wk, Wv, Ws, wtb);

    hipMemsetAsync(bcount, 0, NBMAX * 4, stream);
    const int p1_blocks = (E + CHUNK - 1) / CHUNK;
    b_hist_kernel<<<p1_blocks, 256, 0, stream>>>(dst, bcount, E);
    b_scan_kernel<<<1, NBMAX, 0, stream>>>(bcount, bbase, gcursor, E);
    b_scatter_kernel<<<p1_blocks, 256, 0, stream>>>(src, dst, gcursor, packed, E);
    b_final_kernel<<<NB, 256, 0, stream>>>(packed, bbase, esrc, offs, counts, N);

    const int proj_blocks = (N + 31) / 32;
    const int node_blocks = (N + 15) / 16;

    const ushort_t* cur = xb;
    for (int l = 0; l < LAYERS; ++l) {
        const int last = (l == LAYERS - 1);
        ushort_t* hb_out = (l & 1) ? hb1 : hb0;

        proj_kernel<<<proj_blocks, 256, 0, stream>>>(
            cur, wtb + (size_t)l * 4 * D * D,
            bq + (size_t)l * D, bk + (size_t)l * D,
            bv + (size_t)l * D, bs + (size_t)l * D,
            qb, kv, sk, N);

        node_kernel<<<node_blocks, 256, 0, stream>>>(
            qb, (const uint4*)kv, esrc, offs, counts, sk,
            hb_out, (float*)d_out, N, last ? 1 : 0);

        cur = hb_out;
    }
}